// Round 1
// baseline (303.405 us; speedup 1.0000x reference)
//
#include <hip/hip_runtime.h>
#include <stdint.h>

#define HH   512
#define WWI  512
#define HWN  (HH*WWI)
#define KK   256
#define WSR  32
#define SSW  64
#define PDD  5
#define CAND_CAP 4096

// workspace byte offsets
#define OFF_MASK   0u
#define OFF_MAXP   (1u<<20)
#define OFF_LAB    (2u<<20)
#define OFF_BITS   (3u<<20)                       // 256*64*8 = 131072
#define OFF_AREA   (OFF_BITS + 131072u)           // 3276800
#define OFF_MSUM   (OFF_AREA + 1024u)
#define OFF_CNT    (OFF_MSUM + 1024u)             // 3278848
#define OFF_CNT256 (OFF_CNT + 4u)
#define OFF_ZEND   (OFF_CNT256 + 4u)              // zero region end: 3278856
#define OFF_CY     OFF_ZEND
#define OFF_CX     (OFF_CY + 1024u)
#define OFF_WY0    (OFF_CX + 1024u)
#define OFF_WX0    (OFF_WY0 + 1024u)
#define OFF_FINAL  (OFF_WX0 + 1024u)
#define OFF_ADJ    (OFF_FINAL + 1024u)            // 3283976, 8-aligned; 256*4*8=8192
#define OFF_CAND   (OFF_ADJ + 8192u)              // 3292168; 4096*8=32768

__device__ __forceinline__ float sigm(float v) {
    return 1.0f / (1.0f + expf(-v));
}

__global__ void k_mask(const float* __restrict__ x4, float* __restrict__ mm) {
    int p = blockIdx.x * blockDim.x + threadIdx.x;
    if (p < HWN) mm[p] = sigm(x4[p]);
}

__global__ void k_peaks(const float* __restrict__ mm,
                        unsigned long long* __restrict__ cand, int* __restrict__ counter) {
    int p = blockIdx.x * blockDim.x + threadIdx.x;
    if (p >= HWN) return;
    float m = mm[p];
    if (!(m > 0.7f)) return;
    int y = p >> 9, x = p & 511;
    int y0 = max(y - PDD, 0), y1 = min(y + PDD, HH - 1);
    int x0 = max(x - PDD, 0), x1 = min(x + PDD, WWI - 1);
    for (int yy = y0; yy <= y1; ++yy) {
        const float* row = mm + yy * WWI;
        for (int xx = x0; xx <= x1; ++xx) {
            if (row[xx] > m) return;   // strictly greater neighbor -> not the window max
        }
    }
    int pos = atomicAdd(counter, 1);
    if (pos < CAND_CAP) {
        unsigned long long key =
            ((unsigned long long)__float_as_uint(m) << 32) |
            (unsigned long long)(0xFFFFFFFFu - (unsigned)p);
        cand[pos] = key;
    }
}

__global__ __launch_bounds__(256) void k_sort(const unsigned long long* __restrict__ cand,
                                              const int* __restrict__ counter,
                                              int* __restrict__ cnt256,
                                              int* __restrict__ icy, int* __restrict__ icx,
                                              int* __restrict__ iy0, int* __restrict__ ix0) {
    __shared__ unsigned long long key[CAND_CAP];
    int tid = threadIdx.x;
    int cnt = *counter;
    if (cnt > CAND_CAP) cnt = CAND_CAP;
    for (int i = tid; i < CAND_CAP; i += 256) key[i] = (i < cnt) ? cand[i] : 0ull;
    __syncthreads();
    // bitonic sort, descending
    for (int k = 2; k <= CAND_CAP; k <<= 1) {
        for (int j = k >> 1; j > 0; j >>= 1) {
            for (int i = tid; i < CAND_CAP; i += 256) {
                int ixj = i ^ j;
                if (ixj > i) {
                    unsigned long long a = key[i], b = key[ixj];
                    bool up = ((i & k) == 0);
                    if (up ? (a < b) : (a > b)) { key[i] = b; key[ixj] = a; }
                }
            }
            __syncthreads();
        }
    }
    int m = cnt < KK ? cnt : KK;
    if (tid == 0) *cnt256 = m;
    if (tid < m) {
        unsigned p = 0xFFFFFFFFu - (unsigned)(key[tid] & 0xFFFFFFFFull);
        int cy = (int)(p >> 9), cx = (int)(p & 511);
        icy[tid] = cy; icx[tid] = cx;
        int wy = cy < WSR ? WSR : (cy > HH - WSR ? HH - WSR : cy);
        int wx = cx < WSR ? WSR : (cx > WWI - WSR ? WWI - WSR : cx);
        iy0[tid] = wy - WSR; ix0[tid] = wx - WSR;
    }
}

__global__ __launch_bounds__(256) void k_win(const float* __restrict__ x,
        const float* __restrict__ wc, const float* __restrict__ bc,
        const float* __restrict__ mm, const int* __restrict__ cnt256,
        const int* __restrict__ icy, const int* __restrict__ icx,
        const int* __restrict__ iy0, const int* __restrict__ ix0,
        float* __restrict__ probs, unsigned int* __restrict__ maxp,
        unsigned long long* __restrict__ bits,
        float* __restrict__ areas, float* __restrict__ msum) {
    int k = blockIdx.x, tid = threadIdx.x;
    int cnt = *cnt256;
    if (k >= cnt) {
        for (int i = tid; i < SSW * SSW; i += 256) probs[k * 4096 + i] = 0.0f;
        return;
    }
    __shared__ unsigned long long rb[64];
    __shared__ float sA, sM;
    if (tid < 64) rb[tid] = 0ull;
    if (tid == 0) { sA = 0.0f; sM = 0.0f; }
    __syncthreads();
    float w0 = wc[0], w1 = wc[1], w2 = wc[2], w3 = wc[3], b = bc[0];
    float cyf = (float)icy[k], cxf = (float)icx[k];
    int gy0 = iy0[k], gx0 = ix0[k];
    int r = tid >> 2, cb = (tid & 3) << 4;
    int gy = gy0 + r;
    float gyf = (float)gy;
    const float* x0 = x;
    const float* x1 = x + HWN;
    const float* x2 = x + 2 * HWN;
    const float* x3 = x + 3 * HWN;
    unsigned int bloc = 0;
    float aA = 0.0f, aM = 0.0f;
    int rowbase = gy * WWI;
    for (int q = 0; q < 16; ++q) {
        int col = cb + q;
        int gx = gx0 + col;
        int g = rowbase + gx;
        float d0 = __fsub_rn(__fadd_rn(x0[g], gyf), cyf);
        float d1 = __fsub_rn(__fadd_rn(x1[g], (float)gx), cxf);
        float s0 = x2[g], s1 = x3[g];
        float t = __fadd_rn(
                    __fadd_rn(
                      __fadd_rn(
                        __fadd_rn(__fmul_rn(w0, d0), __fmul_rn(w1, d1)),
                        __fmul_rn(w2, s0)),
                      __fmul_rn(w3, s1)),
                    b);
        float pr = sigm(t);
        probs[k * 4096 + r * 64 + col] = pr;
        if (pr > 0.53f) {
            bloc |= (1u << q);
            aA += 1.0f;
            aM += mm[g];
            atomicMax(&maxp[g], __float_as_uint(pr));
        }
    }
    if (bloc) atomicOr(&rb[r], (unsigned long long)bloc << cb);
    atomicAdd(&sA, aA);
    atomicAdd(&sM, aM);
    __syncthreads();
    if (tid < 64) bits[k * 64 + tid] = rb[tid];
    if (tid == 0) { areas[k] = sA; msum[k] = sM; }
}

__global__ __launch_bounds__(256) void k_lab(const int* __restrict__ cnt256,
        const int* __restrict__ iy0, const int* __restrict__ ix0,
        const float* __restrict__ probs, const unsigned int* __restrict__ maxp,
        int* __restrict__ lab) {
    int k = blockIdx.x, tid = threadIdx.x;
    if (k >= *cnt256) return;
    int gy0 = iy0[k], gx0 = ix0[k];
    for (int q = 0; q < 16; ++q) {
        int p = tid + (q << 8);
        float pr = probs[k * 4096 + p];
        if (pr > 0.53f) {
            int r = p >> 6, c = p & 63;
            int g = (gy0 + r) * WWI + gx0 + c;
            if (pr >= __uint_as_float(maxp[g])) atomicMax(&lab[g], k + 1);
        }
    }
}

__global__ __launch_bounds__(256) void k_pairs(const int* __restrict__ iy0,
        const int* __restrict__ ix0, const unsigned long long* __restrict__ bits,
        const float* __restrict__ areas, unsigned long long* __restrict__ adj) {
    int a = blockIdx.x, b = threadIdx.x;
    __shared__ unsigned long long rowA[64];
    __shared__ int say0, sax0;
    if (threadIdx.x < 64) rowA[threadIdx.x] = bits[a * 64 + threadIdx.x];
    if (threadIdx.x == 0) { say0 = iy0[a]; sax0 = ix0[a]; }
    __syncthreads();
    int ay0 = say0, ax0 = sax0;
    int by0 = iy0[b], bx0 = ix0[b];
    int yl = max(ay0, by0), yh = min(ay0 + SSW, by0 + SSW);
    int xl = max(ax0, bx0), xh = min(ax0 + SSW, bx0 + SSW);
    int inter = 0;
    if (yl < yh && xl < xh) {
        int wdt = xh - xl;
        unsigned long long cmask = (wdt >= 64) ? ~0ull : ((1ull << wdt) - 1ull);
        int sa = xl - ax0, sb = xl - bx0;
        for (int y = yl; y < yh; ++y) {
            unsigned long long wa = rowA[y - ay0] >> sa;
            unsigned long long wb = bits[b * 64 + (y - by0)] >> sb;
            inter += __popcll(wa & wb & cmask);
        }
    }
    float fi = (float)inter;
    float uni = __fsub_rn(__fadd_rn(areas[a], areas[b]), fi);
    bool adjb = (fi / fmaxf(uni, 1.0f)) > 0.3f;
    unsigned long long bal = __ballot(adjb);
    if ((threadIdx.x & 63) == 0) adj[a * 4 + (threadIdx.x >> 6)] = bal;
}

__global__ __launch_bounds__(256) void k_cc(const unsigned long long* __restrict__ adj,
        const float* __restrict__ areas, const float* __restrict__ msum,
        const int* __restrict__ cnt256, int* __restrict__ finalmap) {
    __shared__ unsigned long long adjS[KK][4];
    __shared__ int lbl[KK];
    __shared__ unsigned char rem[KK];
    int i = threadIdx.x;
    for (int w = 0; w < 4; ++w) adjS[i][w] = adj[i * 4 + w];
    lbl[i] = i;
    __syncthreads();
    for (int it = 0; it < 32; ++it) {
        int m = KK;
        for (int w = 0; w < 4; ++w) {
            unsigned long long bb = adjS[i][w];
            while (bb) {
                int j = __ffsll((unsigned long long)bb) - 1;
                int v = lbl[(w << 6) | j];
                m = v < m ? v : m;
                bb &= bb - 1;
            }
        }
        __syncthreads();
        lbl[i] = m;
        __syncthreads();
    }
    float area = areas[i];
    bool validf = i < *cnt256;
    float mean = msum[i] / fmaxf(area, 1.0f);
    rem[i] = (unsigned char)(!((mean > 0.0f) && (area > 10.0f) && validf));
    __syncthreads();
    int root = lbl[i];
    int rc = root < 255 ? root : 255;
    finalmap[i] = rem[rc] ? 0 : (root + 1);
}

__global__ void k_final(const int* __restrict__ lab, const int* __restrict__ finalmap,
                        float* __restrict__ labels) {
    int p = blockIdx.x * blockDim.x + threadIdx.x;
    if (p < HWN) {
        int l = lab[p];
        labels[p] = l > 0 ? (float)finalmap[l - 1] : 0.0f;
    }
}

extern "C" void kernel_launch(void* const* d_in, const int* in_sizes, int n_in,
                              void* d_out, int out_size, void* d_ws, size_t ws_size,
                              hipStream_t stream) {
    const float* x  = (const float*)d_in[0];
    const float* wc = (const float*)d_in[1];
    const float* bc = (const float*)d_in[2];
    float* labels = (float*)d_out;
    float* probs  = (float*)d_out + HWN;

    char* ws = (char*)d_ws;
    float*              mm      = (float*)(ws + OFF_MASK);
    unsigned int*       maxp    = (unsigned int*)(ws + OFF_MAXP);
    int*                lab     = (int*)(ws + OFF_LAB);
    unsigned long long* bits    = (unsigned long long*)(ws + OFF_BITS);
    float*              areas   = (float*)(ws + OFF_AREA);
    float*              msum    = (float*)(ws + OFF_MSUM);
    int*                counter = (int*)(ws + OFF_CNT);
    int*                cnt256  = (int*)(ws + OFF_CNT256);
    int*                icy     = (int*)(ws + OFF_CY);
    int*                icx     = (int*)(ws + OFF_CX);
    int*                iy0     = (int*)(ws + OFF_WY0);
    int*                ix0     = (int*)(ws + OFF_WX0);
    int*                fmap    = (int*)(ws + OFF_FINAL);
    unsigned long long* adj     = (unsigned long long*)(ws + OFF_ADJ);
    unsigned long long* cand    = (unsigned long long*)(ws + OFF_CAND);

    // zero: maxp, lab, bits, areas, msum, counter, cnt256  (one contiguous region)
    hipMemsetAsync(ws + OFF_MAXP, 0, OFF_ZEND - OFF_MAXP, stream);

    k_mask <<<HWN / 256, 256, 0, stream>>>(x + 4 * HWN, mm);
    k_peaks<<<HWN / 256, 256, 0, stream>>>(mm, cand, counter);
    k_sort <<<1, 256, 0, stream>>>(cand, counter, cnt256, icy, icx, iy0, ix0);
    k_win  <<<KK, 256, 0, stream>>>(x, wc, bc, mm, cnt256, icy, icx, iy0, ix0,
                                    probs, maxp, bits, areas, msum);
    k_lab  <<<KK, 256, 0, stream>>>(cnt256, iy0, ix0, probs, maxp, lab);
    k_pairs<<<KK, 256, 0, stream>>>(iy0, ix0, bits, areas, adj);
    k_cc   <<<1, 256, 0, stream>>>(adj, areas, msum, cnt256, fmap);
    k_final<<<HWN / 256, 256, 0, stream>>>(lab, fmap, labels);
}

// Round 2
// 175.641 us; speedup vs baseline: 1.7274x; 1.7274x over previous
//
#include <hip/hip_runtime.h>
#include <stdint.h>

#define HH   512
#define WWI  512
#define HWN  (HH*WWI)
#define KK   256
#define WSR  32
#define SSW  64
#define PDD  5
#define CAND_CAP 4096

// workspace byte offsets
#define OFF_MASK   0u
#define OFF_MAXP   (1u<<20)
#define OFF_LAB    (2u<<20)
#define OFF_BITS   (3u<<20)                       // 256*64*8 = 131072
#define OFF_AREA   (OFF_BITS + 131072u)           // 3276800
#define OFF_MSUM   (OFF_AREA + 1024u)
#define OFF_CNT    (OFF_MSUM + 1024u)             // 3278848
#define OFF_CNT256 (OFF_CNT + 4u)
#define OFF_ZEND   (OFF_CNT256 + 4u)              // zero region end: 3278856
#define OFF_CY     OFF_ZEND
#define OFF_CX     (OFF_CY + 1024u)
#define OFF_WY0    (OFF_CX + 1024u)
#define OFF_WX0    (OFF_WY0 + 1024u)
#define OFF_FINAL  (OFF_WX0 + 1024u)
#define OFF_ADJ    (OFF_FINAL + 1024u)            // 3283976, 8-aligned; 256*4*8=8192
#define OFF_CAND   (OFF_ADJ + 8192u)              // 3292168; 4096*8=32768

__device__ __forceinline__ float sigm(float v) {
    return 1.0f / (1.0f + expf(-v));
}

__global__ void k_mask(const float* __restrict__ x4, float* __restrict__ mm) {
    int p = blockIdx.x * blockDim.x + threadIdx.x;
    if (p < HWN) mm[p] = sigm(x4[p]);
}

__global__ void k_peaks(const float* __restrict__ mm,
                        unsigned long long* __restrict__ cand, int* __restrict__ counter) {
    int p = blockIdx.x * blockDim.x + threadIdx.x;
    if (p >= HWN) return;
    float m = mm[p];
    if (!(m > 0.7f)) return;
    int y = p >> 9, x = p & 511;
    int y0 = max(y - PDD, 0), y1 = min(y + PDD, HH - 1);
    int x0 = max(x - PDD, 0), x1 = min(x + PDD, WWI - 1);
    for (int yy = y0; yy <= y1; ++yy) {
        const float* row = mm + yy * WWI;
        for (int xx = x0; xx <= x1; ++xx) {
            if (row[xx] > m) return;   // strictly greater neighbor -> not the window max
        }
    }
    int pos = atomicAdd(counter, 1);
    if (pos < CAND_CAP) {
        unsigned long long key =
            ((unsigned long long)__float_as_uint(m) << 32) |
            (unsigned long long)(0xFFFFFFFFu - (unsigned)p);
        cand[pos] = key;
    }
}

// 1024-thread pair-indexed bitonic sort, descending, 4096 keys.
__global__ __launch_bounds__(1024) void k_sort(const unsigned long long* __restrict__ cand,
                                               const int* __restrict__ counter,
                                               int* __restrict__ cnt256,
                                               int* __restrict__ icy, int* __restrict__ icx,
                                               int* __restrict__ iy0, int* __restrict__ ix0) {
    __shared__ unsigned long long key[CAND_CAP];
    int tid = threadIdx.x;
    int cnt = *counter;
    if (cnt > CAND_CAP) cnt = CAND_CAP;
    for (int i = tid; i < CAND_CAP; i += 1024) key[i] = (i < cnt) ? cand[i] : 0ull;
    __syncthreads();
    for (int k = 2; k <= CAND_CAP; k <<= 1) {
        for (int j = k >> 1; j > 0; j >>= 1) {
            #pragma unroll
            for (int u = 0; u < CAND_CAP / 2048; ++u) {   // 2 pairs per thread
                int t = tid + u * 1024;
                int i = ((t & ~(j - 1)) << 1) | (t & (j - 1));
                int ixj = i | j;
                unsigned long long a = key[i], b = key[ixj];
                bool desc = ((i & k) == 0);
                if (desc ? (a < b) : (a > b)) { key[i] = b; key[ixj] = a; }
            }
            __syncthreads();
        }
    }
    int m = cnt < KK ? cnt : KK;
    if (tid == 0) *cnt256 = m;
    if (tid < m) {
        unsigned p = 0xFFFFFFFFu - (unsigned)(key[tid] & 0xFFFFFFFFull);
        int cy = (int)(p >> 9), cx = (int)(p & 511);
        icy[tid] = cy; icx[tid] = cx;
        int wy = cy < WSR ? WSR : (cy > HH - WSR ? HH - WSR : cy);
        int wx = cx < WSR ? WSR : (cx > WWI - WSR ? WWI - WSR : cx);
        iy0[tid] = wy - WSR; ix0[tid] = wx - WSR;
    }
}

__global__ __launch_bounds__(256) void k_win(const float* __restrict__ x,
        const float* __restrict__ wc, const float* __restrict__ bc,
        const float* __restrict__ mm, const int* __restrict__ cnt256,
        const int* __restrict__ icy, const int* __restrict__ icx,
        const int* __restrict__ iy0, const int* __restrict__ ix0,
        float* __restrict__ probs, unsigned int* __restrict__ maxp,
        unsigned long long* __restrict__ bits,
        float* __restrict__ areas, float* __restrict__ msum) {
    int k = blockIdx.x, tid = threadIdx.x;
    int cnt = *cnt256;
    if (k >= cnt) {
        for (int i = tid; i < SSW * SSW; i += 256) probs[k * 4096 + i] = 0.0f;
        return;
    }
    __shared__ unsigned long long rb[64];
    __shared__ float sA, sM;
    if (tid < 64) rb[tid] = 0ull;
    if (tid == 0) { sA = 0.0f; sM = 0.0f; }
    __syncthreads();
    float w0 = wc[0], w1 = wc[1], w2 = wc[2], w3 = wc[3], b = bc[0];
    float cyf = (float)icy[k], cxf = (float)icx[k];
    int gy0 = iy0[k], gx0 = ix0[k];
    int r = tid >> 2, cb = (tid & 3) << 4;
    int gy = gy0 + r;
    float gyf = (float)gy;
    const float* x0 = x;
    const float* x1 = x + HWN;
    const float* x2 = x + 2 * HWN;
    const float* x3 = x + 3 * HWN;
    unsigned int bloc = 0;
    float aA = 0.0f, aM = 0.0f;
    int rowbase = gy * WWI;
    for (int q = 0; q < 16; ++q) {
        int col = cb + q;
        int gx = gx0 + col;
        int g = rowbase + gx;
        float d0 = __fsub_rn(__fadd_rn(x0[g], gyf), cyf);
        float d1 = __fsub_rn(__fadd_rn(x1[g], (float)gx), cxf);
        float s0 = x2[g], s1 = x3[g];
        float t = __fadd_rn(
                    __fadd_rn(
                      __fadd_rn(
                        __fadd_rn(__fmul_rn(w0, d0), __fmul_rn(w1, d1)),
                        __fmul_rn(w2, s0)),
                      __fmul_rn(w3, s1)),
                    b);
        float pr = sigm(t);
        probs[k * 4096 + r * 64 + col] = pr;
        if (pr > 0.53f) {
            bloc |= (1u << q);
            aA += 1.0f;
            aM += mm[g];
            atomicMax(&maxp[g], __float_as_uint(pr));
        }
    }
    if (bloc) atomicOr(&rb[r], (unsigned long long)bloc << cb);
    atomicAdd(&sA, aA);
    atomicAdd(&sM, aM);
    __syncthreads();
    if (tid < 64) bits[k * 64 + tid] = rb[tid];
    if (tid == 0) { areas[k] = sA; msum[k] = sM; }
}

__global__ __launch_bounds__(256) void k_lab(const int* __restrict__ cnt256,
        const int* __restrict__ iy0, const int* __restrict__ ix0,
        const float* __restrict__ probs, const unsigned int* __restrict__ maxp,
        int* __restrict__ lab) {
    int k = blockIdx.x, tid = threadIdx.x;
    if (k >= *cnt256) return;
    int gy0 = iy0[k], gx0 = ix0[k];
    for (int q = 0; q < 16; ++q) {
        int p = tid + (q << 8);
        float pr = probs[k * 4096 + p];
        if (pr > 0.53f) {
            int r = p >> 6, c = p & 63;
            int g = (gy0 + r) * WWI + gx0 + c;
            if (pr >= __uint_as_float(maxp[g])) atomicMax(&lab[g], k + 1);
        }
    }
}

__global__ __launch_bounds__(256) void k_pairs(const int* __restrict__ iy0,
        const int* __restrict__ ix0, const unsigned long long* __restrict__ bits,
        const float* __restrict__ areas, unsigned long long* __restrict__ adj) {
    int a = blockIdx.x, b = threadIdx.x;
    __shared__ unsigned long long rowA[64];
    __shared__ int say0, sax0;
    if (threadIdx.x < 64) rowA[threadIdx.x] = bits[a * 64 + threadIdx.x];
    if (threadIdx.x == 0) { say0 = iy0[a]; sax0 = ix0[a]; }
    __syncthreads();
    int ay0 = say0, ax0 = sax0;
    int by0 = iy0[b], bx0 = ix0[b];
    int yl = max(ay0, by0), yh = min(ay0 + SSW, by0 + SSW);
    int xl = max(ax0, bx0), xh = min(ax0 + SSW, bx0 + SSW);
    int inter = 0;
    if (yl < yh && xl < xh) {
        int wdt = xh - xl;
        unsigned long long cmask = (wdt >= 64) ? ~0ull : ((1ull << wdt) - 1ull);
        int sa = xl - ax0, sb = xl - bx0;
        for (int y = yl; y < yh; ++y) {
            unsigned long long wa = rowA[y - ay0] >> sa;
            unsigned long long wb = bits[b * 64 + (y - by0)] >> sb;
            inter += __popcll(wa & wb & cmask);
        }
    }
    float fi = (float)inter;
    float uni = __fsub_rn(__fadd_rn(areas[a], areas[b]), fi);
    bool adjb = (fi / fmaxf(uni, 1.0f)) > 0.3f;
    unsigned long long bal = __ballot(adjb);
    if ((threadIdx.x & 63) == 0) adj[a * 4 + (threadIdx.x >> 6)] = bal;
}

__global__ __launch_bounds__(256) void k_cc(const unsigned long long* __restrict__ adj,
        const float* __restrict__ areas, const float* __restrict__ msum,
        const int* __restrict__ cnt256, int* __restrict__ finalmap) {
    __shared__ unsigned long long adjS[KK][4];
    __shared__ int lbl[KK];
    __shared__ unsigned char rem[KK];
    int i = threadIdx.x;
    for (int w = 0; w < 4; ++w) adjS[i][w] = adj[i * 4 + w];
    lbl[i] = i;
    __syncthreads();
    for (int it = 0; it < 32; ++it) {
        int m = KK;
        for (int w = 0; w < 4; ++w) {
            unsigned long long bb = adjS[i][w];
            while (bb) {
                int j = __ffsll((unsigned long long)bb) - 1;
                int v = lbl[(w << 6) | j];
                m = v < m ? v : m;
                bb &= bb - 1;
            }
        }
        __syncthreads();
        lbl[i] = m;
        __syncthreads();
    }
    float area = areas[i];
    bool validf = i < *cnt256;
    float mean = msum[i] / fmaxf(area, 1.0f);
    rem[i] = (unsigned char)(!((mean > 0.0f) && (area > 10.0f) && validf));
    __syncthreads();
    int root = lbl[i];
    int rc = root < 255 ? root : 255;
    finalmap[i] = rem[rc] ? 0 : (root + 1);
}

__global__ void k_final(const int* __restrict__ lab, const int* __restrict__ finalmap,
                        float* __restrict__ labels) {
    int p = blockIdx.x * blockDim.x + threadIdx.x;
    if (p < HWN) {
        int l = lab[p];
        labels[p] = l > 0 ? (float)finalmap[l - 1] : 0.0f;
    }
}

extern "C" void kernel_launch(void* const* d_in, const int* in_sizes, int n_in,
                              void* d_out, int out_size, void* d_ws, size_t ws_size,
                              hipStream_t stream) {
    const float* x  = (const float*)d_in[0];
    const float* wc = (const float*)d_in[1];
    const float* bc = (const float*)d_in[2];
    float* labels = (float*)d_out;
    float* probs  = (float*)d_out + HWN;

    char* ws = (char*)d_ws;
    float*              mm      = (float*)(ws + OFF_MASK);
    unsigned int*       maxp    = (unsigned int*)(ws + OFF_MAXP);
    int*                lab     = (int*)(ws + OFF_LAB);
    unsigned long long* bits    = (unsigned long long*)(ws + OFF_BITS);
    float*              areas   = (float*)(ws + OFF_AREA);
    float*              msum    = (float*)(ws + OFF_MSUM);
    int*                counter = (int*)(ws + OFF_CNT);
    int*                cnt256  = (int*)(ws + OFF_CNT256);
    int*                icy     = (int*)(ws + OFF_CY);
    int*                icx     = (int*)(ws + OFF_CX);
    int*                iy0     = (int*)(ws + OFF_WY0);
    int*                ix0     = (int*)(ws + OFF_WX0);
    int*                fmap    = (int*)(ws + OFF_FINAL);
    unsigned long long* adj     = (unsigned long long*)(ws + OFF_ADJ);
    unsigned long long* cand    = (unsigned long long*)(ws + OFF_CAND);

    // zero: maxp, lab, bits, areas, msum, counter, cnt256  (one contiguous region)
    hipMemsetAsync(ws + OFF_MAXP, 0, OFF_ZEND - OFF_MAXP, stream);

    k_mask <<<HWN / 256, 256, 0, stream>>>(x + 4 * HWN, mm);
    k_peaks<<<HWN / 256, 256, 0, stream>>>(mm, cand, counter);
    k_sort <<<1, 1024, 0, stream>>>(cand, counter, cnt256, icy, icx, iy0, ix0);
    k_win  <<<KK, 256, 0, stream>>>(x, wc, bc, mm, cnt256, icy, icx, iy0, ix0,
                                    probs, maxp, bits, areas, msum);
    k_lab  <<<KK, 256, 0, stream>>>(cnt256, iy0, ix0, probs, maxp, lab);
    k_pairs<<<KK, 256, 0, stream>>>(iy0, ix0, bits, areas, adj);
    k_cc   <<<1, 256, 0, stream>>>(adj, areas, msum, cnt256, fmap);
    k_final<<<HWN / 256, 256, 0, stream>>>(lab, fmap, labels);
}

// Round 3
// 151.266 us; speedup vs baseline: 2.0058x; 1.1611x over previous
//
#include <hip/hip_runtime.h>
#include <stdint.h>

#define HH   512
#define WWI  512
#define HWN  (HH*WWI)
#define KK   256
#define WSR  32
#define SSW  64
#define PDD  5
#define CAND_CAP 4096

// workspace byte offsets
#define OFF_MASK   0u
#define OFF_MAXP   (1u<<20)
#define OFF_LAB    (2u<<20)
#define OFF_BITS   (3u<<20)                       // 256*64*8 = 131072
#define OFF_AREA   (OFF_BITS + 131072u)           // 3276800
#define OFF_MSUM   (OFF_AREA + 1024u)
#define OFF_CNT    (OFF_MSUM + 1024u)             // 3278848 (counter, cnt256 adjacent)
#define OFF_CNT256 (OFF_CNT + 4u)
#define OFF_CY     (OFF_CNT256 + 4u)
#define OFF_CX     (OFF_CY + 1024u)
#define OFF_WY0    (OFF_CX + 1024u)
#define OFF_WX0    (OFF_WY0 + 1024u)
#define OFF_FINAL  (OFF_WX0 + 1024u)
#define OFF_ADJ    (OFF_FINAL + 1024u)            // 8-aligned; 256*4*8=8192
#define OFF_CAND   (OFF_ADJ + 8192u)              // 4096*8=32768
#define OFF_HMAX   (OFF_CAND + 32768u)            // 1 MB row-max buffer

__device__ __forceinline__ float sigm(float v) {
    return 1.0f / (1.0f + expf(-v));
}

// Pass A: sigmoid + horizontal 11-max (LDS row tile) + all zero-fills fused.
__global__ __launch_bounds__(256) void k_prep(const float* __restrict__ x4,
        float* __restrict__ mm, float* __restrict__ hmax,
        unsigned int* __restrict__ maxp, int* __restrict__ lab,
        unsigned long long* __restrict__ bits,
        float* __restrict__ areas, float* __restrict__ msum,
        int* __restrict__ counters) {
    __shared__ float s[268];
    int t = threadIdx.x, bid = blockIdx.x;
    int row = bid >> 1;
    int x0 = (bid & 1) << 8;
    const float* xr = x4 + row * WWI;
    {   // slot j holds sigm at column clamp(x0-5+j)
        int c = x0 - 5 + t; c = c < 0 ? 0 : (c > 511 ? 511 : c);
        s[t] = sigm(xr[c]);
    }
    if (t < 10) {
        int c = x0 + 251 + t; c = c > 511 ? 511 : c;
        s[256 + t] = sigm(xr[c]);
    }
    __syncthreads();
    float own = s[t + 5];
    int gid = row * WWI + x0 + t;
    mm[gid] = own;
    float h = own;
    #pragma unroll
    for (int d = 0; d < 11; ++d) h = fmaxf(h, s[t + d]);
    hmax[gid] = h;
    // fused zero-fills (replaces hipMemsetAsync)
    int g = bid * 256 + t;
    maxp[g] = 0u;
    lab[g] = 0;
    if (g < KK * 64) bits[g] = 0ull;
    if (g < KK) { areas[g] = 0.0f; msum[g] = 0.0f; }
    if (g < 2) counters[g] = 0;
}

// Pass B: vertical 11-max + peak test + candidate emit.
__global__ __launch_bounds__(256) void k_vpeak(const float* __restrict__ mm,
        const float* __restrict__ hmax,
        unsigned long long* __restrict__ cand, int* __restrict__ counter) {
    int p = blockIdx.x * 256 + threadIdx.x;
    float m = mm[p];
    int y = p >> 9, x = p & 511;
    float v = -1.0f;
    #pragma unroll
    for (int d = -5; d <= 5; ++d) {
        int yy = y + d; yy = yy < 0 ? 0 : (yy > 511 ? 511 : yy);
        v = fmaxf(v, hmax[yy * WWI + x]);
    }
    if (m > 0.7f && m == v) {
        int pos = atomicAdd(counter, 1);
        if (pos < CAND_CAP) {
            cand[pos] = ((unsigned long long)__float_as_uint(m) << 32)
                      | (unsigned long long)(0xFFFFFFFFu - (unsigned)p);
        }
    }
}

// 1024-thread pair-indexed bitonic sort, descending, 4096 keys.
// Barriers only for j>=64; j<=32 steps are wave-private 128-elem segments.
__global__ __launch_bounds__(1024) void k_sort(const unsigned long long* __restrict__ cand,
                                               const int* __restrict__ counter,
                                               int* __restrict__ cnt256,
                                               int* __restrict__ icy, int* __restrict__ icx,
                                               int* __restrict__ iy0, int* __restrict__ ix0) {
    __shared__ unsigned long long key[CAND_CAP];
    int tid = threadIdx.x;
    int cnt = *counter;
    if (cnt > CAND_CAP) cnt = CAND_CAP;
    for (int i = tid; i < CAND_CAP; i += 1024) key[i] = (i < cnt) ? cand[i] : 0ull;
    __syncthreads();
    for (int k = 2; k <= CAND_CAP; k <<= 1) {
        int j = k >> 1;
        for (; j >= 64; j >>= 1) {
            #pragma unroll
            for (int u = 0; u < 2; ++u) {
                int t = tid + u * 1024;
                int i = ((t & ~(j - 1)) << 1) | (t & (j - 1));
                int ixj = i | j;
                unsigned long long a = key[i], b = key[ixj];
                bool desc = ((i & k) == 0);
                if (desc ? (a < b) : (a > b)) { key[i] = b; key[ixj] = a; }
            }
            __syncthreads();
        }
        for (; j >= 1; j >>= 1) {   // wave-private: no barrier needed
            #pragma unroll
            for (int u = 0; u < 2; ++u) {
                int t = tid + u * 1024;
                int i = ((t & ~(j - 1)) << 1) | (t & (j - 1));
                int ixj = i | j;
                unsigned long long a = key[i], b = key[ixj];
                bool desc = ((i & k) == 0);
                if (desc ? (a < b) : (a > b)) { key[i] = b; key[ixj] = a; }
            }
        }
        __syncthreads();
    }
    int m = cnt < KK ? cnt : KK;
    if (tid == 0) *cnt256 = m;
    if (tid < m) {
        unsigned p = 0xFFFFFFFFu - (unsigned)(key[tid] & 0xFFFFFFFFull);
        int cy = (int)(p >> 9), cx = (int)(p & 511);
        icy[tid] = cy; icx[tid] = cx;
        int wy = cy < WSR ? WSR : (cy > HH - WSR ? HH - WSR : cy);
        int wx = cx < WSR ? WSR : (cx > WWI - WSR ? WWI - WSR : cx);
        iy0[tid] = wy - WSR; ix0[tid] = wx - WSR;
    }
}

__global__ __launch_bounds__(256) void k_win(const float* __restrict__ x,
        const float* __restrict__ wc, const float* __restrict__ bc,
        const float* __restrict__ mm, const int* __restrict__ cnt256,
        const int* __restrict__ icy, const int* __restrict__ icx,
        const int* __restrict__ iy0, const int* __restrict__ ix0,
        float* __restrict__ probs, unsigned int* __restrict__ maxp,
        unsigned long long* __restrict__ bits,
        float* __restrict__ areas, float* __restrict__ msum) {
    int k = blockIdx.x, tid = threadIdx.x;
    int cnt = *cnt256;
    if (k >= cnt) {
        for (int i = tid; i < SSW * SSW; i += 256) probs[k * 4096 + i] = 0.0f;
        return;
    }
    __shared__ unsigned long long rb[64];
    __shared__ float sA, sM;
    if (tid < 64) rb[tid] = 0ull;
    if (tid == 0) { sA = 0.0f; sM = 0.0f; }
    __syncthreads();
    float w0 = wc[0], w1 = wc[1], w2 = wc[2], w3 = wc[3], b = bc[0];
    float cyf = (float)icy[k], cxf = (float)icx[k];
    int gy0 = iy0[k], gx0 = ix0[k];
    int r = tid >> 2, cb = (tid & 3) << 4;
    int gy = gy0 + r;
    float gyf = (float)gy;
    const float* x0 = x;
    const float* x1 = x + HWN;
    const float* x2 = x + 2 * HWN;
    const float* x3 = x + 3 * HWN;
    unsigned int bloc = 0;
    float aA = 0.0f, aM = 0.0f;
    int rowbase = gy * WWI;
    for (int q = 0; q < 16; ++q) {
        int col = cb + q;
        int gx = gx0 + col;
        int g = rowbase + gx;
        float d0 = __fsub_rn(__fadd_rn(x0[g], gyf), cyf);
        float d1 = __fsub_rn(__fadd_rn(x1[g], (float)gx), cxf);
        float s0 = x2[g], s1 = x3[g];
        float t = __fadd_rn(
                    __fadd_rn(
                      __fadd_rn(
                        __fadd_rn(__fmul_rn(w0, d0), __fmul_rn(w1, d1)),
                        __fmul_rn(w2, s0)),
                      __fmul_rn(w3, s1)),
                    b);
        float pr = sigm(t);
        probs[k * 4096 + r * 64 + col] = pr;
        if (pr > 0.53f) {
            bloc |= (1u << q);
            aA += 1.0f;
            aM += mm[g];
            atomicMax(&maxp[g], __float_as_uint(pr));
        }
    }
    if (bloc) atomicOr(&rb[r], (unsigned long long)bloc << cb);
    atomicAdd(&sA, aA);
    atomicAdd(&sM, aM);
    __syncthreads();
    if (tid < 64) bits[k * 64 + tid] = rb[tid];
    if (tid == 0) { areas[k] = sA; msum[k] = sM; }
}

__global__ __launch_bounds__(256) void k_lab(const int* __restrict__ cnt256,
        const int* __restrict__ iy0, const int* __restrict__ ix0,
        const float* __restrict__ probs, const unsigned int* __restrict__ maxp,
        int* __restrict__ lab) {
    int k = blockIdx.x, tid = threadIdx.x;
    if (k >= *cnt256) return;
    int gy0 = iy0[k], gx0 = ix0[k];
    for (int q = 0; q < 16; ++q) {
        int p = tid + (q << 8);
        float pr = probs[k * 4096 + p];
        if (pr > 0.53f) {
            int r = p >> 6, c = p & 63;
            int g = (gy0 + r) * WWI + gx0 + c;
            if (pr >= __uint_as_float(maxp[g])) atomicMax(&lab[g], k + 1);
        }
    }
}

__global__ __launch_bounds__(256) void k_pairs(const int* __restrict__ iy0,
        const int* __restrict__ ix0, const unsigned long long* __restrict__ bits,
        const float* __restrict__ areas, unsigned long long* __restrict__ adj) {
    int a = blockIdx.x, b = threadIdx.x;
    __shared__ unsigned long long rowA[64];
    __shared__ int say0, sax0;
    if (threadIdx.x < 64) rowA[threadIdx.x] = bits[a * 64 + threadIdx.x];
    if (threadIdx.x == 0) { say0 = iy0[a]; sax0 = ix0[a]; }
    __syncthreads();
    int ay0 = say0, ax0 = sax0;
    int by0 = iy0[b], bx0 = ix0[b];
    int yl = max(ay0, by0), yh = min(ay0 + SSW, by0 + SSW);
    int xl = max(ax0, bx0), xh = min(ax0 + SSW, bx0 + SSW);
    int inter = 0;
    if (yl < yh && xl < xh) {
        int wdt = xh - xl;
        unsigned long long cmask = (wdt >= 64) ? ~0ull : ((1ull << wdt) - 1ull);
        int sa = xl - ax0, sb = xl - bx0;
        for (int y = yl; y < yh; ++y) {
            unsigned long long wa = rowA[y - ay0] >> sa;
            unsigned long long wb = bits[b * 64 + (y - by0)] >> sb;
            inter += __popcll(wa & wb & cmask);
        }
    }
    float fi = (float)inter;
    float uni = __fsub_rn(__fadd_rn(areas[a], areas[b]), fi);
    bool adjb = (fi / fmaxf(uni, 1.0f)) > 0.3f;
    unsigned long long bal = __ballot(adjb);
    if ((threadIdx.x & 63) == 0) adj[a * 4 + (threadIdx.x >> 6)] = bal;
}

__global__ __launch_bounds__(256) void k_cc(const unsigned long long* __restrict__ adj,
        const float* __restrict__ areas, const float* __restrict__ msum,
        const int* __restrict__ cnt256, int* __restrict__ finalmap) {
    __shared__ unsigned long long adjS[KK][4];
    __shared__ int lbl[KK];
    __shared__ unsigned char rem[KK];
    int i = threadIdx.x;
    for (int w = 0; w < 4; ++w) adjS[i][w] = adj[i * 4 + w];
    lbl[i] = i;
    __syncthreads();
    for (int it = 0; it < 32; ++it) {
        int m = KK;
        for (int w = 0; w < 4; ++w) {
            unsigned long long bb = adjS[i][w];
            while (bb) {
                int j = __ffsll((unsigned long long)bb) - 1;
                int v = lbl[(w << 6) | j];
                m = v < m ? v : m;
                bb &= bb - 1;
            }
        }
        __syncthreads();
        lbl[i] = m;
        __syncthreads();
    }
    float area = areas[i];
    bool validf = i < *cnt256;
    float mean = msum[i] / fmaxf(area, 1.0f);
    rem[i] = (unsigned char)(!((mean > 0.0f) && (area > 10.0f) && validf));
    __syncthreads();
    int root = lbl[i];
    int rc = root < 255 ? root : 255;
    finalmap[i] = rem[rc] ? 0 : (root + 1);
}

__global__ void k_final(const int* __restrict__ lab, const int* __restrict__ finalmap,
                        float* __restrict__ labels) {
    int p = blockIdx.x * blockDim.x + threadIdx.x;
    if (p < HWN) {
        int l = lab[p];
        labels[p] = l > 0 ? (float)finalmap[l - 1] : 0.0f;
    }
}

extern "C" void kernel_launch(void* const* d_in, const int* in_sizes, int n_in,
                              void* d_out, int out_size, void* d_ws, size_t ws_size,
                              hipStream_t stream) {
    const float* x  = (const float*)d_in[0];
    const float* wc = (const float*)d_in[1];
    const float* bc = (const float*)d_in[2];
    float* labels = (float*)d_out;
    float* probs  = (float*)d_out + HWN;

    char* ws = (char*)d_ws;
    float*              mm      = (float*)(ws + OFF_MASK);
    unsigned int*       maxp    = (unsigned int*)(ws + OFF_MAXP);
    int*                lab     = (int*)(ws + OFF_LAB);
    unsigned long long* bits    = (unsigned long long*)(ws + OFF_BITS);
    float*              areas   = (float*)(ws + OFF_AREA);
    float*              msum    = (float*)(ws + OFF_MSUM);
    int*                counter = (int*)(ws + OFF_CNT);
    int*                cnt256  = (int*)(ws + OFF_CNT256);
    int*                icy     = (int*)(ws + OFF_CY);
    int*                icx     = (int*)(ws + OFF_CX);
    int*                iy0     = (int*)(ws + OFF_WY0);
    int*                ix0     = (int*)(ws + OFF_WX0);
    int*                fmap    = (int*)(ws + OFF_FINAL);
    unsigned long long* adj     = (unsigned long long*)(ws + OFF_ADJ);
    unsigned long long* cand    = (unsigned long long*)(ws + OFF_CAND);
    float*              hmax    = (float*)(ws + OFF_HMAX);

    k_prep <<<HWN / 256, 256, 0, stream>>>(x + 4 * HWN, mm, hmax, maxp, lab,
                                           bits, areas, msum, counter);
    k_vpeak<<<HWN / 256, 256, 0, stream>>>(mm, hmax, cand, counter);
    k_sort <<<1, 1024, 0, stream>>>(cand, counter, cnt256, icy, icx, iy0, ix0);
    k_win  <<<KK, 256, 0, stream>>>(x, wc, bc, mm, cnt256, icy, icx, iy0, ix0,
                                    probs, maxp, bits, areas, msum);
    k_lab  <<<KK, 256, 0, stream>>>(cnt256, iy0, ix0, probs, maxp, lab);
    k_pairs<<<KK, 256, 0, stream>>>(iy0, ix0, bits, areas, adj);
    k_cc   <<<1, 256, 0, stream>>>(adj, areas, msum, cnt256, fmap);
    k_final<<<HWN / 256, 256, 0, stream>>>(lab, fmap, labels);
}

// Round 4
// 141.088 us; speedup vs baseline: 2.1505x; 1.0721x over previous
//
#include <hip/hip_runtime.h>
#include <stdint.h>

#define HH   512
#define WWI  512
#define HWN  (HH*WWI)
#define KK   256
#define WSR  32
#define SSW  64
#define PDD  5
#define CAND_CAP 4096

// workspace byte offsets
#define OFF_MASK   0u
#define OFF_MAXP   (1u<<20)
#define OFF_LAB    (2u<<20)
#define OFF_BITS   (3u<<20)                       // 256*64*8 = 131072
#define OFF_AREA   (OFF_BITS + 131072u)
#define OFF_MSUM   (OFF_AREA + 1024u)
#define OFF_CNT    (OFF_MSUM + 1024u)
#define OFF_CNT256 (OFF_CNT + 4u)
#define OFF_CY     (OFF_CNT256 + 4u)
#define OFF_CX     (OFF_CY + 1024u)
#define OFF_WY0    (OFF_CX + 1024u)
#define OFF_WX0    (OFF_WY0 + 1024u)
#define OFF_FINAL  (OFF_WX0 + 1024u)
#define OFF_ADJ    (OFF_FINAL + 1024u)            // 8-aligned; 256*4*8=8192
#define OFF_CAND   (OFF_ADJ + 8192u)              // 4096*8=32768
#define OFF_HMAX   (OFF_CAND + 32768u)            // 1 MB row-max buffer

__device__ __forceinline__ float sigm(float v) {
    return 1.0f / (1.0f + expf(-v));
}

// Pass A: sigmoid + horizontal 11-max (LDS row tile) + all zero-fills fused.
__global__ __launch_bounds__(256) void k_prep(const float* __restrict__ x4,
        float* __restrict__ mm, float* __restrict__ hmax,
        unsigned int* __restrict__ maxp, int* __restrict__ lab,
        unsigned long long* __restrict__ bits,
        float* __restrict__ areas, float* __restrict__ msum,
        int* __restrict__ counters) {
    __shared__ float s[268];
    int t = threadIdx.x, bid = blockIdx.x;
    int row = bid >> 1;
    int x0 = (bid & 1) << 8;
    const float* xr = x4 + row * WWI;
    {   // slot j holds sigm at column clamp(x0-5+j)
        int c = x0 - 5 + t; c = c < 0 ? 0 : (c > 511 ? 511 : c);
        s[t] = sigm(xr[c]);
    }
    if (t < 10) {
        int c = x0 + 251 + t; c = c > 511 ? 511 : c;
        s[256 + t] = sigm(xr[c]);
    }
    __syncthreads();
    float own = s[t + 5];
    int gid = row * WWI + x0 + t;
    mm[gid] = own;
    float h = own;
    #pragma unroll
    for (int d = 0; d < 11; ++d) h = fmaxf(h, s[t + d]);
    hmax[gid] = h;
    // fused zero-fills (replaces hipMemsetAsync)
    int g = bid * 256 + t;
    maxp[g] = 0u;
    lab[g] = 0;
    if (g < KK * 64) bits[g] = 0ull;
    if (g < KK) { areas[g] = 0.0f; msum[g] = 0.0f; }
    if (g < 2) counters[g] = 0;
}

// Pass B: vertical 11-max + peak test + candidate emit.
__global__ __launch_bounds__(256) void k_vpeak(const float* __restrict__ mm,
        const float* __restrict__ hmax,
        unsigned long long* __restrict__ cand, int* __restrict__ counter) {
    int p = blockIdx.x * 256 + threadIdx.x;
    float m = mm[p];
    int y = p >> 9, x = p & 511;
    float v = -1.0f;
    #pragma unroll
    for (int d = -5; d <= 5; ++d) {
        int yy = y + d; yy = yy < 0 ? 0 : (yy > 511 ? 511 : yy);
        v = fmaxf(v, hmax[yy * WWI + x]);
    }
    if (m > 0.7f && m == v) {
        int pos = atomicAdd(counter, 1);
        if (pos < CAND_CAP) {
            cand[pos] = ((unsigned long long)__float_as_uint(m) << 32)
                      | (unsigned long long)(0xFFFFFFFFu - (unsigned)p);
        }
    }
}

// O(n^2) parallel rank selection: thread i computes the exact descending-sort
// rank of candidate i (keys are unique: value bits || ~pixel-index), writes
// its window metadata to slot `rank` if rank < 256. Replaces bitonic sort.
__global__ __launch_bounds__(256) void k_rank(const unsigned long long* __restrict__ cand,
                                              const int* __restrict__ counter,
                                              int* __restrict__ cnt256,
                                              int* __restrict__ icy, int* __restrict__ icx,
                                              int* __restrict__ iy0, int* __restrict__ ix0) {
    __shared__ unsigned long long kl[1024];
    int tid = threadIdx.x;
    int i = blockIdx.x * 256 + tid;
    int cnt = *counter;
    if (cnt > CAND_CAP) cnt = CAND_CAP;
    if (i == 0) *cnt256 = cnt < KK ? cnt : KK;
    if (blockIdx.x * 256 >= cnt) return;   // no candidates in this block
    unsigned long long my = (i < cnt) ? cand[i] : 0ull;
    int rank = 0;
    for (int base = 0; base < cnt; base += 1024) {
        int nload = cnt - base; if (nload > 1024) nload = 1024;
        __syncthreads();
        for (int j = tid; j < nload; j += 256) kl[j] = cand[base + j];
        __syncthreads();
        if (i < cnt) {
            int j = 0;
            for (; j + 4 <= nload; j += 4) {
                rank += (kl[j] > my) + (kl[j+1] > my) + (kl[j+2] > my) + (kl[j+3] > my);
            }
            for (; j < nload; ++j) rank += (kl[j] > my);
        }
    }
    if (i < cnt && rank < KK) {
        unsigned p = 0xFFFFFFFFu - (unsigned)(my & 0xFFFFFFFFull);
        int cy = (int)(p >> 9), cx = (int)(p & 511);
        icy[rank] = cy; icx[rank] = cx;
        int wy = cy < WSR ? WSR : (cy > HH - WSR ? HH - WSR : cy);
        int wx = cx < WSR ? WSR : (cx > WWI - WSR ? WWI - WSR : cx);
        iy0[rank] = wy - WSR; ix0[rank] = wx - WSR;
    }
}

__global__ __launch_bounds__(256) void k_win(const float* __restrict__ x,
        const float* __restrict__ wc, const float* __restrict__ bc,
        const float* __restrict__ mm, const int* __restrict__ cnt256,
        const int* __restrict__ icy, const int* __restrict__ icx,
        const int* __restrict__ iy0, const int* __restrict__ ix0,
        float* __restrict__ probs, unsigned int* __restrict__ maxp,
        unsigned long long* __restrict__ bits,
        float* __restrict__ areas, float* __restrict__ msum) {
    int k = blockIdx.x, tid = threadIdx.x;
    int cnt = *cnt256;
    if (k >= cnt) {
        for (int i = tid; i < SSW * SSW; i += 256) probs[k * 4096 + i] = 0.0f;
        return;
    }
    __shared__ unsigned long long rb[64];
    __shared__ float sA, sM;
    if (tid < 64) rb[tid] = 0ull;
    if (tid == 0) { sA = 0.0f; sM = 0.0f; }
    __syncthreads();
    float w0 = wc[0], w1 = wc[1], w2 = wc[2], w3 = wc[3], b = bc[0];
    float cyf = (float)icy[k], cxf = (float)icx[k];
    int gy0 = iy0[k], gx0 = ix0[k];
    int r = tid >> 2, cb = (tid & 3) << 4;
    int gy = gy0 + r;
    float gyf = (float)gy;
    const float* x0 = x;
    const float* x1 = x + HWN;
    const float* x2 = x + 2 * HWN;
    const float* x3 = x + 3 * HWN;
    unsigned int bloc = 0;
    float aA = 0.0f, aM = 0.0f;
    int rowbase = gy * WWI;
    for (int q = 0; q < 16; ++q) {
        int col = cb + q;
        int gx = gx0 + col;
        int g = rowbase + gx;
        float d0 = __fsub_rn(__fadd_rn(x0[g], gyf), cyf);
        float d1 = __fsub_rn(__fadd_rn(x1[g], (float)gx), cxf);
        float s0 = x2[g], s1 = x3[g];
        float t = __fadd_rn(
                    __fadd_rn(
                      __fadd_rn(
                        __fadd_rn(__fmul_rn(w0, d0), __fmul_rn(w1, d1)),
                        __fmul_rn(w2, s0)),
                      __fmul_rn(w3, s1)),
                    b);
        float pr = sigm(t);
        probs[k * 4096 + r * 64 + col] = pr;
        if (pr > 0.53f) {
            bloc |= (1u << q);
            aA += 1.0f;
            aM += mm[g];
            atomicMax(&maxp[g], __float_as_uint(pr));
        }
    }
    if (bloc) atomicOr(&rb[r], (unsigned long long)bloc << cb);
    atomicAdd(&sA, aA);
    atomicAdd(&sM, aM);
    __syncthreads();
    if (tid < 64) bits[k * 64 + tid] = rb[tid];
    if (tid == 0) { areas[k] = sA; msum[k] = sM; }
}

__global__ __launch_bounds__(256) void k_lab(const int* __restrict__ cnt256,
        const int* __restrict__ iy0, const int* __restrict__ ix0,
        const float* __restrict__ probs, const unsigned int* __restrict__ maxp,
        int* __restrict__ lab) {
    int k = blockIdx.x, tid = threadIdx.x;
    if (k >= *cnt256) return;
    int gy0 = iy0[k], gx0 = ix0[k];
    for (int q = 0; q < 16; ++q) {
        int p = tid + (q << 8);
        float pr = probs[k * 4096 + p];
        if (pr > 0.53f) {
            int r = p >> 6, c = p & 63;
            int g = (gy0 + r) * WWI + gx0 + c;
            if (pr >= __uint_as_float(maxp[g])) atomicMax(&lab[g], k + 1);
        }
    }
}

__global__ __launch_bounds__(256) void k_pairs(const int* __restrict__ iy0,
        const int* __restrict__ ix0, const unsigned long long* __restrict__ bits,
        const float* __restrict__ areas, unsigned long long* __restrict__ adj) {
    int a = blockIdx.x, b = threadIdx.x;
    __shared__ unsigned long long rowA[64];
    __shared__ int say0, sax0;
    if (threadIdx.x < 64) rowA[threadIdx.x] = bits[a * 64 + threadIdx.x];
    if (threadIdx.x == 0) { say0 = iy0[a]; sax0 = ix0[a]; }
    __syncthreads();
    int ay0 = say0, ax0 = sax0;
    int by0 = iy0[b], bx0 = ix0[b];
    int yl = max(ay0, by0), yh = min(ay0 + SSW, by0 + SSW);
    int xl = max(ax0, bx0), xh = min(ax0 + SSW, bx0 + SSW);
    int inter = 0;
    if (yl < yh && xl < xh) {
        int wdt = xh - xl;
        unsigned long long cmask = (wdt >= 64) ? ~0ull : ((1ull << wdt) - 1ull);
        int sa = xl - ax0, sb = xl - bx0;
        for (int y = yl; y < yh; ++y) {
            unsigned long long wa = rowA[y - ay0] >> sa;
            unsigned long long wb = bits[b * 64 + (y - by0)] >> sb;
            inter += __popcll(wa & wb & cmask);
        }
    }
    float fi = (float)inter;
    float uni = __fsub_rn(__fadd_rn(areas[a], areas[b]), fi);
    bool adjb = (fi / fmaxf(uni, 1.0f)) > 0.3f;
    unsigned long long bal = __ballot(adjb);
    if ((threadIdx.x & 63) == 0) adj[a * 4 + (threadIdx.x >> 6)] = bal;
}

__global__ __launch_bounds__(256) void k_cc(const unsigned long long* __restrict__ adj,
        const float* __restrict__ areas, const float* __restrict__ msum,
        const int* __restrict__ cnt256, int* __restrict__ finalmap) {
    __shared__ unsigned long long adjS[KK][4];
    __shared__ int lbl[KK];
    __shared__ unsigned char rem[KK];
    __shared__ int changed;
    int i = threadIdx.x;
    for (int w = 0; w < 4; ++w) adjS[i][w] = adj[i * 4 + w];
    lbl[i] = i;
    __syncthreads();
    for (int it = 0; it < 32; ++it) {
        int m = KK;
        for (int w = 0; w < 4; ++w) {
            unsigned long long bb = adjS[i][w];
            while (bb) {
                int j = __ffsll((unsigned long long)bb) - 1;
                int v = lbl[(w << 6) | j];
                m = v < m ? v : m;
                bb &= bb - 1;
            }
        }
        if (i == 0) changed = 0;
        __syncthreads();
        if (m != lbl[i]) { lbl[i] = m; atomicOr(&changed, 1); }
        __syncthreads();
        if (!changed) break;   // converged: further iterations are identity
    }
    float area = areas[i];
    bool validf = i < *cnt256;
    float mean = msum[i] / fmaxf(area, 1.0f);
    rem[i] = (unsigned char)(!((mean > 0.0f) && (area > 10.0f) && validf));
    __syncthreads();
    int root = lbl[i];
    int rc = root < 255 ? root : 255;
    finalmap[i] = rem[rc] ? 0 : (root + 1);
}

__global__ void k_final(const int* __restrict__ lab, const int* __restrict__ finalmap,
                        float* __restrict__ labels) {
    int p = blockIdx.x * blockDim.x + threadIdx.x;
    if (p < HWN) {
        int l = lab[p];
        labels[p] = l > 0 ? (float)finalmap[l - 1] : 0.0f;
    }
}

extern "C" void kernel_launch(void* const* d_in, const int* in_sizes, int n_in,
                              void* d_out, int out_size, void* d_ws, size_t ws_size,
                              hipStream_t stream) {
    const float* x  = (const float*)d_in[0];
    const float* wc = (const float*)d_in[1];
    const float* bc = (const float*)d_in[2];
    float* labels = (float*)d_out;
    float* probs  = (float*)d_out + HWN;

    char* ws = (char*)d_ws;
    float*              mm      = (float*)(ws + OFF_MASK);
    unsigned int*       maxp    = (unsigned int*)(ws + OFF_MAXP);
    int*                lab     = (int*)(ws + OFF_LAB);
    unsigned long long* bits    = (unsigned long long*)(ws + OFF_BITS);
    float*              areas   = (float*)(ws + OFF_AREA);
    float*              msum    = (float*)(ws + OFF_MSUM);
    int*                counter = (int*)(ws + OFF_CNT);
    int*                cnt256  = (int*)(ws + OFF_CNT256);
    int*                icy     = (int*)(ws + OFF_CY);
    int*                icx     = (int*)(ws + OFF_CX);
    int*                iy0     = (int*)(ws + OFF_WY0);
    int*                ix0     = (int*)(ws + OFF_WX0);
    int*                fmap    = (int*)(ws + OFF_FINAL);
    unsigned long long* adj     = (unsigned long long*)(ws + OFF_ADJ);
    unsigned long long* cand    = (unsigned long long*)(ws + OFF_CAND);
    float*              hmax    = (float*)(ws + OFF_HMAX);

    k_prep <<<HWN / 256, 256, 0, stream>>>(x + 4 * HWN, mm, hmax, maxp, lab,
                                           bits, areas, msum, counter);
    k_vpeak<<<HWN / 256, 256, 0, stream>>>(mm, hmax, cand, counter);
    k_rank <<<CAND_CAP / 256, 256, 0, stream>>>(cand, counter, cnt256, icy, icx, iy0, ix0);
    k_win  <<<KK, 256, 0, stream>>>(x, wc, bc, mm, cnt256, icy, icx, iy0, ix0,
                                    probs, maxp, bits, areas, msum);
    k_lab  <<<KK, 256, 0, stream>>>(cnt256, iy0, ix0, probs, maxp, lab);
    k_pairs<<<KK, 256, 0, stream>>>(iy0, ix0, bits, areas, adj);
    k_cc   <<<1, 256, 0, stream>>>(adj, areas, msum, cnt256, fmap);
    k_final<<<HWN / 256, 256, 0, stream>>>(lab, fmap, labels);
}

// Round 5
// 105.778 us; speedup vs baseline: 2.8683x; 1.3338x over previous
//
#include <hip/hip_runtime.h>
#include <stdint.h>

#define HH   512
#define WWI  512
#define HWN  (HH*WWI)
#define KK   256
#define WSR  32
#define SSW  64
#define PDD  5
#define CAND_CAP 4096

// workspace byte offsets
#define OFF_MASK   0u
#define OFF_MAXP   (1u<<20)
#define OFF_LAB    (2u<<20)
#define OFF_BITS   (3u<<20)                       // 256*64*8 = 131072
#define OFF_AREA   (OFF_BITS + 131072u)
#define OFF_MSUM   (OFF_AREA + 1024u)
#define OFF_CNT    (OFF_MSUM + 1024u)
#define OFF_CNT256 (OFF_CNT + 4u)
#define OFF_CY     (OFF_CNT256 + 4u)
#define OFF_CX     (OFF_CY + 1024u)
#define OFF_WY0    (OFF_CX + 1024u)
#define OFF_WX0    (OFF_WY0 + 1024u)
#define OFF_FINAL  (OFF_WX0 + 1024u)
#define OFF_ADJ    (OFF_FINAL + 1024u)            // 8-aligned; 256*4*8=8192
#define OFF_CAND   (OFF_ADJ + 8192u)              // 4096*8=32768
#define OFF_HMAX   (OFF_CAND + 32768u)            // 1 MB row-max buffer
#define OFF_RANK   (OFF_HMAX + (HWN*4u))          // 4096*4 = 16 KB

__device__ __forceinline__ float sigm(float v) {
    return 1.0f / (1.0f + expf(-v));
}

// Pass A: sigmoid + horizontal 11-max (LDS row tile) + all zero-fills fused.
__global__ __launch_bounds__(256) void k_prep(const float* __restrict__ x4,
        float* __restrict__ mm, float* __restrict__ hmax,
        unsigned int* __restrict__ maxp, int* __restrict__ lab,
        unsigned long long* __restrict__ bits,
        float* __restrict__ areas, float* __restrict__ msum,
        int* __restrict__ counters, int* __restrict__ rankbuf) {
    __shared__ float s[268];
    int t = threadIdx.x, bid = blockIdx.x;
    int row = bid >> 1;
    int x0 = (bid & 1) << 8;
    const float* xr = x4 + row * WWI;
    {   // slot j holds sigm at column clamp(x0-5+j)
        int c = x0 - 5 + t; c = c < 0 ? 0 : (c > 511 ? 511 : c);
        s[t] = sigm(xr[c]);
    }
    if (t < 10) {
        int c = x0 + 251 + t; c = c > 511 ? 511 : c;
        s[256 + t] = sigm(xr[c]);
    }
    __syncthreads();
    float own = s[t + 5];
    int gid = row * WWI + x0 + t;
    mm[gid] = own;
    float h = own;
    #pragma unroll
    for (int d = 0; d < 11; ++d) h = fmaxf(h, s[t + d]);
    hmax[gid] = h;
    // fused zero-fills (replaces hipMemsetAsync)
    int g = bid * 256 + t;
    maxp[g] = 0u;
    lab[g] = 0;
    if (g < KK * 64) bits[g] = 0ull;
    if (g < CAND_CAP) rankbuf[g] = 0;
    if (g < KK) { areas[g] = 0.0f; msum[g] = 0.0f; }
    if (g < 2) counters[g] = 0;
}

// Pass B: vertical 11-max + peak test + candidate emit.
__global__ __launch_bounds__(256) void k_vpeak(const float* __restrict__ mm,
        const float* __restrict__ hmax,
        unsigned long long* __restrict__ cand, int* __restrict__ counter) {
    int p = blockIdx.x * 256 + threadIdx.x;
    float m = mm[p];
    int y = p >> 9, x = p & 511;
    float v = -1.0f;
    #pragma unroll
    for (int d = -5; d <= 5; ++d) {
        int yy = y + d; yy = yy < 0 ? 0 : (yy > 511 ? 511 : yy);
        v = fmaxf(v, hmax[yy * WWI + x]);
    }
    if (m > 0.7f && m == v) {
        int pos = atomicAdd(counter, 1);
        if (pos < CAND_CAP) {
            cand[pos] = ((unsigned long long)__float_as_uint(m) << 32)
                      | (unsigned long long)(0xFFFFFFFFu - (unsigned)p);
        }
    }
}

// Rank, stage 1: block (bx,by) accumulates partial descending-sort ranks of
// candidates [bx*256,+256) against key chunk [by*256,+256).  atomicAdd of
// ints -> order-independent, deterministic.
__global__ __launch_bounds__(256) void k_rank1(const unsigned long long* __restrict__ cand,
                                               const int* __restrict__ counter,
                                               int* __restrict__ rankbuf) {
    __shared__ unsigned long long kl[256];
    int tid = threadIdx.x;
    int cnt = *counter;
    if (cnt > CAND_CAP) cnt = CAND_CAP;
    int ibase = blockIdx.x * 256;
    int jbase = blockIdx.y * 256;
    if (ibase >= cnt || jbase >= cnt) return;
    int nk = cnt - jbase; if (nk > 256) nk = 256;
    kl[tid] = (tid < nk) ? cand[jbase + tid] : 0ull;   // pad 0: never > any real key
    __syncthreads();
    int i = ibase + tid;
    if (i >= cnt) return;
    unsigned long long my = cand[i];
    int r0 = 0, r1 = 0, r2 = 0, r3 = 0, r4 = 0, r5 = 0, r6 = 0, r7 = 0;
    #pragma unroll 4
    for (int j = 0; j < 256; j += 8) {
        unsigned long long a0 = kl[j+0], a1 = kl[j+1], a2 = kl[j+2], a3 = kl[j+3];
        unsigned long long a4 = kl[j+4], a5 = kl[j+5], a6 = kl[j+6], a7 = kl[j+7];
        r0 += (a0 > my); r1 += (a1 > my); r2 += (a2 > my); r3 += (a3 > my);
        r4 += (a4 > my); r5 += (a5 > my); r6 += (a6 > my); r7 += (a7 > my);
    }
    int r = (r0 + r1) + (r2 + r3) + ((r4 + r5) + (r6 + r7));
    if (r) atomicAdd(&rankbuf[i], r);
}

// Rank, stage 2: place candidate i's window metadata at its final rank slot.
__global__ __launch_bounds__(256) void k_place(const unsigned long long* __restrict__ cand,
                                               const int* __restrict__ counter,
                                               const int* __restrict__ rankbuf,
                                               int* __restrict__ cnt256,
                                               int* __restrict__ icy, int* __restrict__ icx,
                                               int* __restrict__ iy0, int* __restrict__ ix0) {
    int i = blockIdx.x * 256 + threadIdx.x;
    int cnt = *counter;
    if (cnt > CAND_CAP) cnt = CAND_CAP;
    if (i == 0) *cnt256 = cnt < KK ? cnt : KK;
    if (i >= cnt) return;
    int rank = rankbuf[i];
    if (rank >= KK) return;
    unsigned p = 0xFFFFFFFFu - (unsigned)(cand[i] & 0xFFFFFFFFull);
    int cy = (int)(p >> 9), cx = (int)(p & 511);
    icy[rank] = cy; icx[rank] = cx;
    int wy = cy < WSR ? WSR : (cy > HH - WSR ? HH - WSR : cy);
    int wx = cx < WSR ? WSR : (cx > WWI - WSR ? WWI - WSR : cx);
    iy0[rank] = wy - WSR; ix0[rank] = wx - WSR;
}

__global__ __launch_bounds__(256) void k_win(const float* __restrict__ x,
        const float* __restrict__ wc, const float* __restrict__ bc,
        const float* __restrict__ mm, const int* __restrict__ cnt256,
        const int* __restrict__ icy, const int* __restrict__ icx,
        const int* __restrict__ iy0, const int* __restrict__ ix0,
        float* __restrict__ probs, unsigned int* __restrict__ maxp,
        unsigned long long* __restrict__ bits,
        float* __restrict__ areas, float* __restrict__ msum) {
    int k = blockIdx.x, tid = threadIdx.x;
    int cnt = *cnt256;
    if (k >= cnt) {
        for (int i = tid; i < SSW * SSW; i += 256) probs[k * 4096 + i] = 0.0f;
        return;
    }
    __shared__ unsigned long long rb[64];
    __shared__ float sA, sM;
    if (tid < 64) rb[tid] = 0ull;
    if (tid == 0) { sA = 0.0f; sM = 0.0f; }
    __syncthreads();
    float w0 = wc[0], w1 = wc[1], w2 = wc[2], w3 = wc[3], b = bc[0];
    float cyf = (float)icy[k], cxf = (float)icx[k];
    int gy0 = iy0[k], gx0 = ix0[k];
    int r = tid >> 2, cb = (tid & 3) << 4;
    int gy = gy0 + r;
    float gyf = (float)gy;
    const float* x0 = x;
    const float* x1 = x + HWN;
    const float* x2 = x + 2 * HWN;
    const float* x3 = x + 3 * HWN;
    unsigned int bloc = 0;
    float aA = 0.0f, aM = 0.0f;
    int rowbase = gy * WWI;
    for (int q = 0; q < 16; ++q) {
        int col = cb + q;
        int gx = gx0 + col;
        int g = rowbase + gx;
        float d0 = __fsub_rn(__fadd_rn(x0[g], gyf), cyf);
        float d1 = __fsub_rn(__fadd_rn(x1[g], (float)gx), cxf);
        float s0 = x2[g], s1 = x3[g];
        float t = __fadd_rn(
                    __fadd_rn(
                      __fadd_rn(
                        __fadd_rn(__fmul_rn(w0, d0), __fmul_rn(w1, d1)),
                        __fmul_rn(w2, s0)),
                      __fmul_rn(w3, s1)),
                    b);
        float pr = sigm(t);
        probs[k * 4096 + r * 64 + col] = pr;
        if (pr > 0.53f) {
            bloc |= (1u << q);
            aA += 1.0f;
            aM += mm[g];
            atomicMax(&maxp[g], __float_as_uint(pr));
        }
    }
    if (bloc) atomicOr(&rb[r], (unsigned long long)bloc << cb);
    atomicAdd(&sA, aA);
    atomicAdd(&sM, aM);
    __syncthreads();
    if (tid < 64) bits[k * 64 + tid] = rb[tid];
    if (tid == 0) { areas[k] = sA; msum[k] = sM; }
}

__global__ __launch_bounds__(256) void k_lab(const int* __restrict__ cnt256,
        const int* __restrict__ iy0, const int* __restrict__ ix0,
        const float* __restrict__ probs, const unsigned int* __restrict__ maxp,
        int* __restrict__ lab) {
    int k = blockIdx.x, tid = threadIdx.x;
    if (k >= *cnt256) return;
    int gy0 = iy0[k], gx0 = ix0[k];
    for (int q = 0; q < 16; ++q) {
        int p = tid + (q << 8);
        float pr = probs[k * 4096 + p];
        if (pr > 0.53f) {
            int r = p >> 6, c = p & 63;
            int g = (gy0 + r) * WWI + gx0 + c;
            if (pr >= __uint_as_float(maxp[g])) atomicMax(&lab[g], k + 1);
        }
    }
}

__global__ __launch_bounds__(256) void k_pairs(const int* __restrict__ iy0,
        const int* __restrict__ ix0, const unsigned long long* __restrict__ bits,
        const float* __restrict__ areas, unsigned long long* __restrict__ adj) {
    int a = blockIdx.x, b = threadIdx.x;
    __shared__ unsigned long long rowA[64];
    __shared__ int say0, sax0;
    if (threadIdx.x < 64) rowA[threadIdx.x] = bits[a * 64 + threadIdx.x];
    if (threadIdx.x == 0) { say0 = iy0[a]; sax0 = ix0[a]; }
    __syncthreads();
    int ay0 = say0, ax0 = sax0;
    int by0 = iy0[b], bx0 = ix0[b];
    int yl = max(ay0, by0), yh = min(ay0 + SSW, by0 + SSW);
    int xl = max(ax0, bx0), xh = min(ax0 + SSW, bx0 + SSW);
    int inter = 0;
    if (yl < yh && xl < xh) {
        int wdt = xh - xl;
        unsigned long long cmask = (wdt >= 64) ? ~0ull : ((1ull << wdt) - 1ull);
        int sa = xl - ax0, sb = xl - bx0;
        for (int y = yl; y < yh; ++y) {
            unsigned long long wa = rowA[y - ay0] >> sa;
            unsigned long long wb = bits[b * 64 + (y - by0)] >> sb;
            inter += __popcll(wa & wb & cmask);
        }
    }
    float fi = (float)inter;
    float uni = __fsub_rn(__fadd_rn(areas[a], areas[b]), fi);
    bool adjb = (fi / fmaxf(uni, 1.0f)) > 0.3f;
    unsigned long long bal = __ballot(adjb);
    if ((threadIdx.x & 63) == 0) adj[a * 4 + (threadIdx.x >> 6)] = bal;
}

__global__ __launch_bounds__(256) void k_cc(const unsigned long long* __restrict__ adj,
        const float* __restrict__ areas, const float* __restrict__ msum,
        const int* __restrict__ cnt256, int* __restrict__ finalmap) {
    __shared__ unsigned long long adjS[KK][4];
    __shared__ int lbl[KK];
    __shared__ unsigned char rem[KK];
    __shared__ int changed;
    int i = threadIdx.x;
    for (int w = 0; w < 4; ++w) adjS[i][w] = adj[i * 4 + w];
    lbl[i] = i;
    __syncthreads();
    for (int it = 0; it < 32; ++it) {
        int m = KK;
        for (int w = 0; w < 4; ++w) {
            unsigned long long bb = adjS[i][w];
            while (bb) {
                int j = __ffsll((unsigned long long)bb) - 1;
                int v = lbl[(w << 6) | j];
                m = v < m ? v : m;
                bb &= bb - 1;
            }
        }
        if (i == 0) changed = 0;
        __syncthreads();
        if (m != lbl[i]) { lbl[i] = m; atomicOr(&changed, 1); }
        __syncthreads();
        if (!changed) break;   // converged: further iterations are identity
    }
    float area = areas[i];
    bool validf = i < *cnt256;
    float mean = msum[i] / fmaxf(area, 1.0f);
    rem[i] = (unsigned char)(!((mean > 0.0f) && (area > 10.0f) && validf));
    __syncthreads();
    int root = lbl[i];
    int rc = root < 255 ? root : 255;
    finalmap[i] = rem[rc] ? 0 : (root + 1);
}

__global__ void k_final(const int* __restrict__ lab, const int* __restrict__ finalmap,
                        float* __restrict__ labels) {
    int p = blockIdx.x * blockDim.x + threadIdx.x;
    if (p < HWN) {
        int l = lab[p];
        labels[p] = l > 0 ? (float)finalmap[l - 1] : 0.0f;
    }
}

extern "C" void kernel_launch(void* const* d_in, const int* in_sizes, int n_in,
                              void* d_out, int out_size, void* d_ws, size_t ws_size,
                              hipStream_t stream) {
    const float* x  = (const float*)d_in[0];
    const float* wc = (const float*)d_in[1];
    const float* bc = (const float*)d_in[2];
    float* labels = (float*)d_out;
    float* probs  = (float*)d_out + HWN;

    char* ws = (char*)d_ws;
    float*              mm      = (float*)(ws + OFF_MASK);
    unsigned int*       maxp    = (unsigned int*)(ws + OFF_MAXP);
    int*                lab     = (int*)(ws + OFF_LAB);
    unsigned long long* bits    = (unsigned long long*)(ws + OFF_BITS);
    float*              areas   = (float*)(ws + OFF_AREA);
    float*              msum    = (float*)(ws + OFF_MSUM);
    int*                counter = (int*)(ws + OFF_CNT);
    int*                cnt256  = (int*)(ws + OFF_CNT256);
    int*                icy     = (int*)(ws + OFF_CY);
    int*                icx     = (int*)(ws + OFF_CX);
    int*                iy0     = (int*)(ws + OFF_WY0);
    int*                ix0     = (int*)(ws + OFF_WX0);
    int*                fmap    = (int*)(ws + OFF_FINAL);
    unsigned long long* adj     = (unsigned long long*)(ws + OFF_ADJ);
    unsigned long long* cand    = (unsigned long long*)(ws + OFF_CAND);
    float*              hmax    = (float*)(ws + OFF_HMAX);
    int*                rankbuf = (int*)(ws + OFF_RANK);

    k_prep <<<HWN / 256, 256, 0, stream>>>(x + 4 * HWN, mm, hmax, maxp, lab,
                                           bits, areas, msum, counter, rankbuf);
    k_vpeak<<<HWN / 256, 256, 0, stream>>>(mm, hmax, cand, counter);
    k_rank1<<<dim3(CAND_CAP / 256, CAND_CAP / 256), 256, 0, stream>>>(cand, counter, rankbuf);
    k_place<<<CAND_CAP / 256, 256, 0, stream>>>(cand, counter, rankbuf, cnt256,
                                                icy, icx, iy0, ix0);
    k_win  <<<KK, 256, 0, stream>>>(x, wc, bc, mm, cnt256, icy, icx, iy0, ix0,
                                    probs, maxp, bits, areas, msum);
    k_lab  <<<KK, 256, 0, stream>>>(cnt256, iy0, ix0, probs, maxp, lab);
    k_pairs<<<KK, 256, 0, stream>>>(iy0, ix0, bits, areas, adj);
    k_cc   <<<1, 256, 0, stream>>>(adj, areas, msum, cnt256, fmap);
    k_final<<<HWN / 256, 256, 0, stream>>>(lab, fmap, labels);
}